// Round 5
// baseline (160.491 us; speedup 1.0000x reference)
//
#include <hip/hip_runtime.h>
#include <hip/hip_bf16.h>

#define GAT_N 8192
#define GAT_K 256
#define GAT_D 64
#define GAT_ALPHA 0.2f
#define GAT_FILL 1e-15f

typedef float f32x4 __attribute__((ext_vector_type(4)));
typedef short bf16x8 __attribute__((ext_vector_type(8)));

static __device__ __forceinline__ unsigned f2bf_u(float x) {
  unsigned u = __float_as_uint(x);
  u += 0x7FFFu + ((u >> 16) & 1u);
  return u >> 16;
}

static __device__ __forceinline__ float rfl(float x) {
  return __uint_as_float(__builtin_amdgcn_readfirstlane(__float_as_uint(x)));
}

static __device__ __forceinline__ f32x4 ntload(const float* p) {
  return __builtin_nontemporal_load((const f32x4*)p);
}

// ---------------------------------------------------------------------------
// Kernel 1: register-tiled Wh = h @ W (unchanged from round 4).
// ---------------------------------------------------------------------------
__global__ __launch_bounds__(256) void k_prep(const float* __restrict__ h,
                                              const float* __restrict__ W,
                                              const float* __restrict__ av,
                                              float* __restrict__ s_src,
                                              float* __restrict__ s_dst,
                                              short* __restrict__ WhT,
                                              float* __restrict__ bmax) {
  __shared__ short T[4][64][8];
  __shared__ float wmLds[4];
  const int tid = threadIdx.x;
  const int wv = tid >> 6, lane = tid & 63;
  const int r0 = blockIdx.x * 32 + wv * 8;

  float acc[8], acc2[8];
#pragma unroll
  for (int r = 0; r < 8; ++r) { acc[r] = 0.f; acc2[r] = 0.f; }

  for (int kc = 0; kc < GAT_K; kc += 32) {
    float Wreg[32];
#pragma unroll
    for (int e = 0; e < 32; ++e) Wreg[e] = W[(size_t)(kc + e) * GAT_D + lane];
#pragma unroll
    for (int r = 0; r < 8; ++r) {
      const f32x4* h4 = (const f32x4*)(h + (size_t)(r0 + r) * GAT_K + kc);
#pragma unroll
      for (int q = 0; q < 8; ++q) {
        f32x4 hv = h4[q];
        acc[r] += hv[0] * Wreg[4 * q + 0];
        acc2[r] += hv[1] * Wreg[4 * q + 1];
        acc[r] += hv[2] * Wreg[4 * q + 2];
        acc2[r] += hv[3] * Wreg[4 * q + 3];
      }
    }
  }

  const float a_s = av[lane];
  const float a_d = av[64 + lane];
  float wmax = -3.0e38f;
#pragma unroll
  for (int r = 0; r < 8; ++r) {
    const float accf = acc[r] + acc2[r];
    T[wv][lane][r] = (short)f2bf_u(accf);
    float vs = accf * a_s, vd = accf * a_d;
#pragma unroll
    for (int off = 32; off > 0; off >>= 1) {
      vs += __shfl_xor(vs, off);
      vd += __shfl_xor(vd, off);
    }
    if (lane == 0) { s_src[r0 + r] = vs; s_dst[r0 + r] = vd; }
    wmax = fmaxf(wmax, vd);
  }
  bf16x8 vt = *(const bf16x8*)&T[wv][lane][0];
  *(bf16x8*)(WhT + (size_t)lane * GAT_N + r0) = vt;

  if (lane == 0) wmLds[wv] = wmax;
  __syncthreads();
  if (tid == 0) {
    bmax[blockIdx.x] = fmaxf(fmaxf(wmLds[0], wmLds[1]), fmaxf(wmLds[2], wmLds[3]));
  }
}

// ---------------------------------------------------------------------------
// Kernel 2: fused masked-softmax + P@Wh, fixed-shift softmax.
// Block = 16 rows x 2048-col chunks; each wave OWNS 2 rows for staging.
// Stage: per chunk, 8 independent 1KB loads in flight per wave (ping-pong
// half-buffers; next chunk's first half issued before the MFMA phase, so
// HBM latency hides under MFMA + barriers). P written to the shared
// XOR-swizzled [16][2048] bf16 tile. MFMA: wave wv consumes its disjoint
// 256-col slice (8 kq x 5 MFMAs, +ones B for row-sum). Exact cross-wave
// combine at the end (fixed shift).
// ---------------------------------------------------------------------------
#define BM 16
#define JB 2048
#define NWAVE 8

__global__ __launch_bounds__(512, 4) void k_attn(
    const float* __restrict__ A,
    const float* __restrict__ s_src,
    const float* __restrict__ s_dst,
    const short* __restrict__ WhT,
    const float* __restrict__ bmax,
    float* __restrict__ out) {
  __shared__ char smem[65536];  // P tile [16][2048] bf16 (swizzled); epilogue reuse

  const int tid = threadIdx.x;
  const int wv = tid >> 6, lane = tid & 63;
  const int rsub = lane & 15, kg = lane >> 4;
  const int i0 = blockIdx.x * BM;
  const int r0 = wv * 2, r1 = wv * 2 + 1;  // this wave's stage rows

  const float* A0 = A + (size_t)(i0 + r0) * GAT_N + lane * 4;
  const float* A1 = A + (size_t)(i0 + r1) * GAT_N + lane * 4;

  f32x4 Ra[2][4], Rb[2][4];  // ping-pong half-buffers (4 segs x 2 rows each)
  auto issue = [&](int b, int jcol) {
#pragma unroll
    for (int s = 0; s < 4; ++s) {
      Ra[b][s] = ntload(A0 + jcol + s * 256);
      Rb[b][s] = ntload(A1 + jcol + s * 256);
    }
  };
  issue(0, 0);  // chunk 0, half 0 — in flight during scalar setup below

  // global max of s_dst from 256 per-block maxima
  float bm = fmaxf(fmaxf(bmax[lane], bmax[lane + 64]),
                   fmaxf(bmax[lane + 128], bmax[lane + 192]));
#pragma unroll
  for (int off = 32; off > 0; off >>= 1) bm = fmaxf(bm, __shfl_xor(bm, off));
  const float tmax = bm;

  // per-row (wave-uniform) softmax constants in SGPRs
  const float sA = s_src[i0 + r0];
  const float sB = s_src[i0 + r1];
  float e1a, e2a, ca, e1b, e2b, cb;
  {
    float x0 = sA + tmax;
    float m = fmaxf(fmaxf(x0, GAT_ALPHA * x0), GAT_FILL);
    e1a = rfl(sA - m);
    e2a = rfl(GAT_ALPHA * sA - m);
    ca = rfl(__expf(GAT_FILL - m));
  }
  {
    float x0 = sB + tmax;
    float m = fmaxf(fmaxf(x0, GAT_ALPHA * x0), GAT_FILL);
    e1b = rfl(sB - m);
    e2b = rfl(GAT_ALPHA * sB - m);
    cb = rfl(__expf(GAT_FILL - m));
  }

  bf16x8 ones;
#pragma unroll
  for (int e = 0; e < 8; ++e) ones[e] = (short)0x3F80;

  f32x4 acc0 = {0.f, 0.f, 0.f, 0.f};
  f32x4 acc1 = {0.f, 0.f, 0.f, 0.f};
  f32x4 acc2 = {0.f, 0.f, 0.f, 0.f};
  f32x4 acc3 = {0.f, 0.f, 0.f, 0.f};
  f32x4 accl = {0.f, 0.f, 0.f, 0.f};

  const short* pb0 = WhT + (size_t)(0 * 16 + rsub) * GAT_N;
  const short* pb1 = WhT + (size_t)(1 * 16 + rsub) * GAT_N;
  const short* pb2 = WhT + (size_t)(2 * 16 + rsub) * GAT_N;
  const short* pb3 = WhT + (size_t)(3 * 16 + rsub) * GAT_N;

  auto stage_row = [&](int r, f32x4 av, f32x4 t, float e1, float e2, float cc,
                       int sg) {
    unsigned pk[4];
#pragma unroll
    for (int e = 0; e < 4; ++e) {
      float arg = fmaxf(t[e] + e1, fmaf(GAT_ALPHA, t[e], e2));
      float pe = __expf(arg);
      pe = (av[e] > 0.f) ? pe : cc;
      pk[e] = f2bf_u(pe);
    }
    uint2 w;
    w.x = pk[0] | (pk[1] << 16);
    w.y = pk[2] | (pk[3] << 16);
    *(uint2*)(&smem[(r << 12) + (((sg << 9) | (lane << 3)) ^ ((r & 7) << 4))]) = w;
  };

  auto stage_half = [&](int b, int jc, int half) {
#pragma unroll
    for (int s = 0; s < 4; ++s) {
      const int sg = half * 4 + s;
      const f32x4 t = *(const f32x4*)(s_dst + jc + sg * 256 + lane * 4);
      stage_row(r0, Ra[b][s], t, e1a, e2a, ca, sg);
      stage_row(r1, Rb[b][s], t, e1b, e2b, cb, sg);
    }
  };

  for (int chunk = 0; chunk < GAT_N / JB; ++chunk) {
    const int jc = chunk * JB;
    issue(1, jc + 1024);            // this chunk's half 1
    stage_half(0, jc, 0);
    if (chunk < 3) issue(0, jc + JB);  // next chunk's half 0 (hides under MFMA)
    stage_half(1, jc, 1);
    __syncthreads();

    // ---- MFMA phase: wave wv consumes cols [jc + wv*256, +256) ----
#pragma unroll
    for (int kq = 0; kq < 8; ++kq) {
      const int cbyte = (wv << 9) + (kq << 6) + (kg << 4);
      bf16x8 af = *(const bf16x8*)(&smem[(rsub << 12) + (cbyte ^ ((rsub & 7) << 4))]);
      const int bcol = jc + (wv << 8) + (kq << 5) + (kg << 3);
      bf16x8 b0 = *(const bf16x8*)(pb0 + bcol);
      bf16x8 b1 = *(const bf16x8*)(pb1 + bcol);
      bf16x8 b2 = *(const bf16x8*)(pb2 + bcol);
      bf16x8 b3 = *(const bf16x8*)(pb3 + bcol);
      acc0 = __builtin_amdgcn_mfma_f32_16x16x32_bf16(af, b0, acc0, 0, 0, 0);
      acc1 = __builtin_amdgcn_mfma_f32_16x16x32_bf16(af, b1, acc1, 0, 0, 0);
      acc2 = __builtin_amdgcn_mfma_f32_16x16x32_bf16(af, b2, acc2, 0, 0, 0);
      acc3 = __builtin_amdgcn_mfma_f32_16x16x32_bf16(af, b3, acc3, 0, 0, 0);
      accl = __builtin_amdgcn_mfma_f32_16x16x32_bf16(af, ones, accl, 0, 0, 0);
    }
    __syncthreads();  // protect tile before next stage overwrites
  }

  // ---- epilogue: exact cross-wave combine + ELU (smem reused) ----
  float* lds_o = (float*)smem;            // [8][16][64] f32 = 32 KB
  float* lds_l = (float*)(smem + 32768);  // [8][16]
#pragma unroll
  for (int r = 0; r < 4; ++r) {
    const int orow = kg * 4 + r;  // C/D layout: col = lane&15, row = kg*4+reg
    lds_o[wv * 1024 + orow * 64 + 0 * 16 + rsub] = acc0[r];
    lds_o[wv * 1024 + orow * 64 + 1 * 16 + rsub] = acc1[r];
    lds_o[wv * 1024 + orow * 64 + 2 * 16 + rsub] = acc2[r];
    lds_o[wv * 1024 + orow * 64 + 3 * 16 + rsub] = acc3[r];
    if (rsub == 0) lds_l[wv * 16 + orow] = accl[r];
  }
  __syncthreads();

  for (int idx = tid; idx < BM * GAT_D; idx += 512) {
    const int r = idx >> 6, c = idx & 63;
    float o = 0.f, ll = 0.f;
#pragma unroll
    for (int w = 0; w < NWAVE; ++w) {
      o += lds_o[w * 1024 + r * 64 + c];
      ll += lds_l[w * 16 + r];
    }
    float val = o / ll;
    out[(size_t)(i0 + r) * GAT_D + c] = (val > 0.f) ? val : (__expf(val) - 1.f);
  }
}

// ---------------------------------------------------------------------------
extern "C" void kernel_launch(void* const* d_in, const int* in_sizes, int n_in,
                              void* d_out, int out_size, void* d_ws, size_t ws_size,
                              hipStream_t stream) {
  const float* h = (const float*)d_in[0];
  const float* A = (const float*)d_in[1];
  const float* W = (const float*)d_in[2];
  const float* a = (const float*)d_in[3];
  float* out = (float*)d_out;

  // ws layout: [0,1K) bmax | [4K,+32K) s_src | [36864,+32K) s_dst | [69632,+1M) WhT
  const size_t need = 69632 + (size_t)GAT_D * GAT_N * 2;
  if (ws_size < need) return;
  float* bmax = (float*)d_ws;
  float* s_src = (float*)((char*)d_ws + 4096);
  float* s_dst = (float*)((char*)d_ws + 36864);
  short* WhT = (short*)((char*)d_ws + 69632);

  k_prep<<<dim3(256), dim3(256), 0, stream>>>(h, W, a, s_src, s_dst, WhT, bmax);
  k_attn<<<dim3(GAT_N / BM), dim3(512), 0, stream>>>(A, s_src, s_dst, WhT, bmax, out);
}